// Round 2
// baseline (882.853 us; speedup 1.0000x reference)
//
#include <hip/hip_runtime.h>

// EchoStateNetwork: h_t = tanh(x_t @ W_in + h_{t-1} @ W_res)
//   x: [512,1024,6] f32; W_in: [6,128]; W_res: [128,128]; out: [512,1024,128]
//
// Round 2: fp32, packed-FMA over OUTPUT PAIRS + K-split-4.
//  - 512 blocks (1 batch row each) x 256 thr -> 2 blocks/CU, 8 waves/CU.
//  - thread = (r-pair rp 0..63, K-quarter kq 0..3); kq in lane bits 4..5 so
//    LDS h-reads are broadcast within 16-lane groups (2 distinct addrs per
//    32-lane half = free 2-way aliasing).
//  - W_res slice in VGPRs as float2 pairs (32 x 8B = 64 VGPR), forced into
//    arch VGPRs by the inline-asm "v" constraints (round-1 showed the
//    compiler parking the array in AGPRs: VGPR_Count=48 + accvgpr reads).
//  - v_pk_fma_f32 with op_sel half-broadcast of h: 1 instr = 2 FMAs, no dup movs.
//  - bias channels distributed across kq groups (exactly-once, group3 = zero W).
//  - reduce across kq: shfl_xor 16 then 32; 4 rotating accs break dep chains.

#define SEQ 1024
#define CIN 6
#define RES 128

__device__ __forceinline__ float fast_tanh(float x) {
    // tanh(x) = 1 - 2/(exp2(2*log2e*x)+1); ~1e-7 abs err (validated r1: absmax 3.9e-3)
    float e = __builtin_exp2f(x * 2.88539008177793f);
    return 1.0f - 2.0f * __builtin_amdgcn_rcpf(e + 1.0f);
}

// acc.{lo,hi} += h.lo * w.{lo,hi}   (broadcast low half of src0)
__device__ __forceinline__ void pk_fma_blo(float2& acc, float2 h, float2 w) {
    asm("v_pk_fma_f32 %0, %1, %2, %0 op_sel:[0,0,0] op_sel_hi:[0,1,1]"
        : "+v"(acc) : "v"(h), "v"(w));
}
// acc.{lo,hi} += h.hi * w.{lo,hi}   (broadcast high half of src0)
__device__ __forceinline__ void pk_fma_bhi(float2& acc, float2 h, float2 w) {
    asm("v_pk_fma_f32 %0, %1, %2, %0 op_sel:[1,0,0] op_sel_hi:[1,1,1]"
        : "+v"(acc) : "v"(h), "v"(w));
}

__global__ void esn_fwd(
    const float* __restrict__ x,      // [B, S, 6]
    const float* __restrict__ W_in,   // [6, 128]
    const float* __restrict__ W_res,  // [128, 128]
    float* __restrict__ out)          // [B, S, 128]
{
    __shared__ float x_lds[SEQ * CIN];                    // 24 KB
    __shared__ __align__(16) float2 h_lds[2][RES / 2];    // ping-pong, 1 KB

    const int t    = threadIdx.x;
    const int row  = blockIdx.x;
    const int lane = t & 63;
    const int w    = t >> 6;
    const int kq   = (lane >> 4) & 3;          // K-quarter: k in [32*kq, 32*kq+32)
    const int rp   = (w << 4) | (lane & 15);   // r-pair 0..63
    const int r0   = rp << 1;                  // outputs r0, r0+1

    // Stage this row's x into LDS (coalesced).
    const float* xrow = x + (size_t)row * SEQ * CIN;
    for (int i = t; i < SEQ * CIN; i += 256) x_lds[i] = xrow[i];

    // Bias weights: group g (<3) owns channels 2g, 2g+1; group 3 owns none.
    float2 win0 = make_float2(0.f, 0.f), win1 = make_float2(0.f, 0.f);
    if (kq < 3) {
        win0 = *(const float2*)&W_in[(2 * kq + 0) * RES + r0];
        win1 = *(const float2*)&W_in[(2 * kq + 1) * RES + r0];
    }
    const int cb = (kq < 3) ? 2 * kq : 0;      // x channel base (clamped for kq=3)

    // W_res[kq*32 + j][r0..r0+1] as float2 -> 64 VGPRs.
    float2 w2[32];
#pragma unroll
    for (int j = 0; j < 32; ++j)
        w2[j] = *(const float2*)&W_res[(kq * 32 + j) * RES + r0];

    if (t < 64) h_lds[0][t] = make_float2(0.f, 0.f);
    __syncthreads();

    float* outp = out + (size_t)row * SEQ * RES + r0;

    for (int s = 0; s < SEQ; ++s) {
        // my 32-float K slice of h, as 8 float4 broadcast reads
        const float4* hp = (const float4*)&h_lds[s & 1][0] + (kq << 3);

        float2 a0 = make_float2(0.f, 0.f), a1 = a0, a2 = a0, a3 = a0;

        // bias contribution (exactly-once across kq groups)
        float2 xc = *(const float2*)&x_lds[s * CIN + cb];
        pk_fma_blo(a0, xc, win0);
        pk_fma_bhi(a1, xc, win1);

#pragma unroll
        for (int j = 0; j < 8; ++j) {
            float4 h4 = hp[j];
            float2 hab = make_float2(h4.x, h4.y);   // low pair (subreg)
            float2 hcd = make_float2(h4.z, h4.w);   // high pair (subreg)
            pk_fma_blo(a0, hab, w2[4 * j + 0]);
            pk_fma_bhi(a1, hab, w2[4 * j + 1]);
            pk_fma_blo(a2, hcd, w2[4 * j + 2]);
            pk_fma_bhi(a3, hcd, w2[4 * j + 3]);
        }

        float accx = (a0.x + a1.x) + (a2.x + a3.x);
        float accy = (a0.y + a1.y) + (a2.y + a3.y);

        // combine the 4 K-quarters (partner lanes share the same rp)
        accx += __shfl_xor(accx, 16, 64);
        accy += __shfl_xor(accy, 16, 64);
        accx += __shfl_xor(accx, 32, 64);
        accy += __shfl_xor(accy, 32, 64);

        float2 hv = make_float2(fast_tanh(accx), fast_tanh(accy));

        if (kq == 0) {
            h_lds[(s & 1) ^ 1][rp] = hv;                  // next-step state
            *(float2*)(outp + (size_t)s * RES) = hv;      // 128B/wave contiguous
        }
        __syncthreads();
    }
}

extern "C" void kernel_launch(void* const* d_in, const int* in_sizes, int n_in,
                              void* d_out, int out_size, void* d_ws, size_t ws_size,
                              hipStream_t stream) {
    const float* x     = (const float*)d_in[0];
    const float* W_in  = (const float*)d_in[1];
    const float* W_res = (const float*)d_in[2];
    float* out = (float*)d_out;
    (void)in_sizes; (void)n_in; (void)out_size; (void)d_ws; (void)ws_size;

    esn_fwd<<<512, 256, 0, stream>>>(x, W_in, W_res, out);
}